// Round 3
// baseline (500.236 us; speedup 1.0000x reference)
//
#include <hip/hip_runtime.h>

#define NN 8192
#define DD 128

typedef short s16x4 __attribute__((ext_vector_type(4)));
typedef short s16x8 __attribute__((ext_vector_type(8)));
typedef float f32x4 __attribute__((ext_vector_type(4)));
typedef unsigned short u16;

__device__ __forceinline__ u16 f2bf(float f) {
  unsigned int u = __float_as_uint(f);
  u += 0x7fffu + ((u >> 16) & 1u);   // RNE; inputs are never NaN
  return (u16)(u >> 16);
}
__device__ __forceinline__ float bf2f(u16 h) {
  return __uint_as_float(((unsigned int)h) << 16);
}

// ---- K1: dinv[i] = rsqrt(1 + rowsum(A[i,:]))  AND  Abf = bf16(A) ----
__global__ __launch_bounds__(256) void k_prep(const float* __restrict__ A,
                                              float* __restrict__ dinv,
                                              u16* __restrict__ Abf) {
  const int row = blockIdx.x;
  const float4* Ar = (const float4*)(A + (size_t)row * NN);
  ushort4* Br = (ushort4*)(Abf + (size_t)row * NN);
  const int t = threadIdx.x;
  float s = 0.f;
#pragma unroll
  for (int i = 0; i < 8; ++i) {
    float4 v = Ar[t + 256 * i];
    s += (v.x + v.y) + (v.z + v.w);
    ushort4 b;
    b.x = f2bf(v.x); b.y = f2bf(v.y); b.z = f2bf(v.z); b.w = f2bf(v.w);
    Br[t + 256 * i] = b;
  }
#pragma unroll
  for (int off = 32; off > 0; off >>= 1) s += __shfl_down(s, off, 64);
  __shared__ float red[4];
  if ((t & 63) == 0) red[t >> 6] = s;
  __syncthreads();
  if (t == 0) {
    float d = 1.0f + ((red[0] + red[1]) + (red[2] + red[3]));
    dinv[row] = d > 0.f ? rsqrtf(d) : 0.f;
  }
}

// ---- K2: tT[n][j] = bf16(dinv[j]*(X@W)[j][n]);  out[j][n] = dinv[j]^2*S + bias ----
// The out-write seeds the final result with the bias and the +I diagonal term, so
// k_gemm can accumulate straight into it with atomics (no part[] / k_reduce).
__global__ __launch_bounds__(256) void k_support(const float* __restrict__ X,
                                                 const float* __restrict__ W,
                                                 const float* __restrict__ dinv,
                                                 const float* __restrict__ bias,
                                                 u16* __restrict__ tT,
                                                 float* __restrict__ out) {
  __shared__ __align__(16) u16 Wt[128][136];  // Wt[n][k] = W[k][n]
  __shared__ __align__(16) u16 Xs[32][136];   // Xs[j][k]
  const int t = threadIdx.x;
  const int j0 = blockIdx.x * 32;

  const float4* W4 = (const float4*)W;
#pragma unroll
  for (int s = 0; s < 16; ++s) {
    int c = t + 256 * s;
    int k = c >> 5, n4 = c & 31;
    float4 wv = W4[c];
    Wt[n4 * 4 + 0][k] = f2bf(wv.x);
    Wt[n4 * 4 + 1][k] = f2bf(wv.y);
    Wt[n4 * 4 + 2][k] = f2bf(wv.z);
    Wt[n4 * 4 + 3][k] = f2bf(wv.w);
  }
  const float4* X4 = (const float4*)(X + (size_t)j0 * DD);
#pragma unroll
  for (int s = 0; s < 4; ++s) {
    int c = t + 256 * s;
    int j = c >> 5, q = c & 31;
    float4 xv = X4[c];
    s16x4 p;
    p[0] = (short)f2bf(xv.x); p[1] = (short)f2bf(xv.y);
    p[2] = (short)f2bf(xv.z); p[3] = (short)f2bf(xv.w);
    *(s16x4*)&Xs[j][q * 4] = p;
  }
  __syncthreads();

  const int w = t >> 6, L = t & 63, lrow = L & 15, quad = L >> 4;
  f32x4 acc[2][2] = {};
#pragma unroll
  for (int ks = 0; ks < 4; ++ks) {
    const int k = ks * 32;
    s16x8 fa[2], fb[2];
#pragma unroll
    for (int nt = 0; nt < 2; ++nt)
      fa[nt] = *(const s16x8*)&Wt[w * 32 + nt * 16 + lrow][k + quad * 8];
#pragma unroll
    for (int jt = 0; jt < 2; ++jt)
      fb[jt] = *(const s16x8*)&Xs[jt * 16 + lrow][k + quad * 8];
#pragma unroll
    for (int nt = 0; nt < 2; ++nt)
#pragma unroll
      for (int jt = 0; jt < 2; ++jt)
        acc[nt][jt] = __builtin_amdgcn_mfma_f32_16x16x32_bf16(fa[nt], fb[jt], acc[nt][jt], 0, 0, 0);
  }

#pragma unroll
  for (int jt = 0; jt < 2; ++jt) {
    const int j = j0 + jt * 16 + lrow;
    const float dv = dinv[j];
#pragma unroll
    for (int nt = 0; nt < 2; ++nt) {
#pragma unroll
      for (int r = 0; r < 4; ++r) {
        const int n = w * 32 + nt * 16 + quad * 4 + r;
        const float sv = acc[nt][jt][r];
        tT[(size_t)n * NN + j] = f2bf(dv * sv);
        out[(size_t)j * DD + n] = dv * (dv * sv) + bias[n];  // diag (+I) + bias seed
      }
    }
  }
}

// ---- K3: out[i][n] += dinv[i] * sum_k Abf[i][k] * tT[n][k]  (split-K=2) ----
// Barrier-free: MFMA fragments loaded register-direct from global. B (tT, 2MB)
// is L2-resident; A-frag rows are identical across the block's 4 waves -> L1.
// 512 blocks = 2/CU, 8 waves/CU; 16 independent 16B loads in flight per unroll.
__global__ __launch_bounds__(256) void k_gemm(const u16* __restrict__ Abf,
                                              const u16* __restrict__ tT,
                                              const float* __restrict__ dinv,
                                              float* __restrict__ out) {
  const int t = threadIdx.x;
  const int w = t >> 6, L = t & 63, lrow = L & 15, quad = L >> 4;
  const int bm = blockIdx.x >> 1, kh = blockIdx.x & 1;
  const int i0 = bm * 32;
  const size_t k0 = (size_t)kh * (NN / 2);
  const u16* A0 = Abf + (size_t)(i0 + lrow) * NN + k0 + quad * 8;
  const u16* A1 = A0 + (size_t)16 * NN;
  const u16* B0 = tT + (size_t)(w * 32 + lrow) * NN + k0 + quad * 8;
  const u16* B1 = B0 + (size_t)16 * NN;

  f32x4 acc00 = {}, acc01 = {}, acc10 = {}, acc11 = {};
#pragma unroll 4
  for (int k = 0; k < NN / 2; k += 32) {
    s16x8 fa0 = *(const s16x8*)(A0 + k);
    s16x8 fa1 = *(const s16x8*)(A1 + k);
    s16x8 fb0 = *(const s16x8*)(B0 + k);
    s16x8 fb1 = *(const s16x8*)(B1 + k);
    acc00 = __builtin_amdgcn_mfma_f32_16x16x32_bf16(fa0, fb0, acc00, 0, 0, 0);
    acc01 = __builtin_amdgcn_mfma_f32_16x16x32_bf16(fa0, fb1, acc01, 0, 0, 0);
    acc10 = __builtin_amdgcn_mfma_f32_16x16x32_bf16(fa1, fb0, acc10, 0, 0, 0);
    acc11 = __builtin_amdgcn_mfma_f32_16x16x32_bf16(fa1, fb1, acc11, 0, 0, 0);
  }

  f32x4 accs[2][2] = {{acc00, acc01}, {acc10, acc11}};
#pragma unroll
  for (int mt = 0; mt < 2; ++mt) {
#pragma unroll
    for (int r = 0; r < 4; ++r) {
      const int i = i0 + mt * 16 + quad * 4 + r;
      const float dv = dinv[i];
#pragma unroll
      for (int nt = 0; nt < 2; ++nt) {
        const int n = w * 32 + nt * 16 + lrow;
        unsafeAtomicAdd(&out[(size_t)i * DD + n], dv * accs[mt][nt][r]);
      }
    }
  }
}

extern "C" void kernel_launch(void* const* d_in, const int* in_sizes, int n_in,
                              void* d_out, int out_size, void* d_ws, size_t ws_size,
                              hipStream_t stream) {
  const float* X    = (const float*)d_in[0];   // node_features [8192,128]
  const float* A    = (const float*)d_in[1];   // adj_matrix    [8192,8192]
  const float* W    = (const float*)d_in[2];   // weight        [128,128]
  const float* bias = (const float*)d_in[3];   // bias          [128]
  float* out = (float*)d_out;

  float* dinv = (float*)d_ws;                                  // 32 KB
  u16*   tT   = (u16*)((char*)d_ws + 32768);                   // 2 MB
  u16*   Abf  = (u16*)((char*)d_ws + 32768 + 2097152);         // 128 MB

  hipLaunchKernelGGL(k_prep,    dim3(8192), dim3(256), 0, stream, A, dinv, Abf);
  hipLaunchKernelGGL(k_support, dim3(256),  dim3(256), 0, stream, X, W, dinv, bias, tT, out);
  hipLaunchKernelGGL(k_gemm,    dim3(512),  dim3(256), 0, stream, Abf, tT, dinv, out);
}

// Round 4
// 439.142 us; speedup vs baseline: 1.1391x; 1.1391x over previous
//
#include <hip/hip_runtime.h>

#define NN 8192
#define DD 128

typedef short s16x4 __attribute__((ext_vector_type(4)));
typedef short s16x8 __attribute__((ext_vector_type(8)));
typedef float f32x4 __attribute__((ext_vector_type(4)));
typedef unsigned short u16;
typedef const void __attribute__((address_space(1))) gvoid;
typedef void __attribute__((address_space(3))) lvoid;

__device__ __forceinline__ u16 f2bf(float f) {
  unsigned int u = __float_as_uint(f);
  u += 0x7fffu + ((u >> 16) & 1u);   // RNE; inputs are never NaN
  return (u16)(u >> 16);
}
__device__ __forceinline__ float bf2f(u16 h) {
  return __uint_as_float(((unsigned int)h) << 16);
}

// ---- K1: dinv[i] = rsqrt(1 + rowsum(A[i,:]))  AND  Abf = bf16(A) ----
__global__ __launch_bounds__(256) void k_prep(const float* __restrict__ A,
                                              float* __restrict__ dinv,
                                              u16* __restrict__ Abf) {
  const int row = blockIdx.x;
  const float4* Ar = (const float4*)(A + (size_t)row * NN);
  ushort4* Br = (ushort4*)(Abf + (size_t)row * NN);
  const int t = threadIdx.x;
  float s = 0.f;
#pragma unroll
  for (int i = 0; i < 8; ++i) {
    float4 v = Ar[t + 256 * i];
    s += (v.x + v.y) + (v.z + v.w);
    ushort4 b;
    b.x = f2bf(v.x); b.y = f2bf(v.y); b.z = f2bf(v.z); b.w = f2bf(v.w);
    Br[t + 256 * i] = b;
  }
#pragma unroll
  for (int off = 32; off > 0; off >>= 1) s += __shfl_down(s, off, 64);
  __shared__ float red[4];
  if ((t & 63) == 0) red[t >> 6] = s;
  __syncthreads();
  if (t == 0) {
    float d = 1.0f + ((red[0] + red[1]) + (red[2] + red[3]));
    dinv[row] = d > 0.f ? rsqrtf(d) : 0.f;
  }
}

// ---- K2: tT[n][j] = bf16( dinv[j] * (X @ W)[j][n] ) ----
__global__ __launch_bounds__(256) void k_support(const float* __restrict__ X,
                                                 const float* __restrict__ W,
                                                 const float* __restrict__ dinv,
                                                 u16* __restrict__ tT) {
  __shared__ __align__(16) u16 Wt[128][136];  // Wt[n][k] = W[k][n]
  __shared__ __align__(16) u16 Xs[32][136];   // Xs[j][k]
  const int t = threadIdx.x;
  const int j0 = blockIdx.x * 32;

  const float4* W4 = (const float4*)W;
#pragma unroll
  for (int s = 0; s < 16; ++s) {
    int c = t + 256 * s;
    int k = c >> 5, n4 = c & 31;
    float4 wv = W4[c];
    Wt[n4 * 4 + 0][k] = f2bf(wv.x);
    Wt[n4 * 4 + 1][k] = f2bf(wv.y);
    Wt[n4 * 4 + 2][k] = f2bf(wv.z);
    Wt[n4 * 4 + 3][k] = f2bf(wv.w);
  }
  const float4* X4 = (const float4*)(X + (size_t)j0 * DD);
#pragma unroll
  for (int s = 0; s < 4; ++s) {
    int c = t + 256 * s;
    int j = c >> 5, q = c & 31;
    float4 xv = X4[c];
    s16x4 p;
    p[0] = (short)f2bf(xv.x); p[1] = (short)f2bf(xv.y);
    p[2] = (short)f2bf(xv.z); p[3] = (short)f2bf(xv.w);
    *(s16x4*)&Xs[j][q * 4] = p;
  }
  __syncthreads();

  const int w = t >> 6, L = t & 63, lrow = L & 15, quad = L >> 4;
  f32x4 acc[2][2] = {};
#pragma unroll
  for (int ks = 0; ks < 4; ++ks) {
    const int k = ks * 32;
    s16x8 fa[2], fb[2];
#pragma unroll
    for (int nt = 0; nt < 2; ++nt)
      fa[nt] = *(const s16x8*)&Wt[w * 32 + nt * 16 + lrow][k + quad * 8];
#pragma unroll
    for (int jt = 0; jt < 2; ++jt)
      fb[jt] = *(const s16x8*)&Xs[jt * 16 + lrow][k + quad * 8];
#pragma unroll
    for (int nt = 0; nt < 2; ++nt)
#pragma unroll
      for (int jt = 0; jt < 2; ++jt)
        acc[nt][jt] = __builtin_amdgcn_mfma_f32_16x16x32_bf16(fa[nt], fb[jt], acc[nt][jt], 0, 0, 0);
  }

#pragma unroll
  for (int jt = 0; jt < 2; ++jt) {
    const int j = j0 + jt * 16 + lrow;
    const float dv = dinv[j];
#pragma unroll
    for (int nt = 0; nt < 2; ++nt) {
#pragma unroll
      for (int r = 0; r < 4; ++r) {
        const int n = w * 32 + nt * 16 + quad * 4 + r;
        tT[(size_t)n * NN + j] = f2bf(dv * acc[nt][jt][r]);
      }
    }
  }
}

// ---- K3: part[kq] = Abf[64 rows, kquarter] @ tT[:, kquarter]^T  (split-K=4) ----
// BM=64, BN=128, BK=64. Tile image: A 64x128B (8KB) + B 128x128B (16KB) = 24KB,
// double-buffered = 48KB LDS. global_load_lds width-16; 16B chunks XOR-swizzled
// (chunk ^= row&7) since row stride 128B == 32 banks. Grid 512 = 2 blocks/CU.
#define TILE_BYTES 24576
__global__ __launch_bounds__(256) void k_gemm(const u16* __restrict__ Abf,
                                              const u16* __restrict__ tT,
                                              float* __restrict__ part) {
  __shared__ __align__(16) unsigned char sh[2][TILE_BYTES];
  const int t = threadIdx.x;
  const int bm = blockIdx.x >> 2;       // 0..127
  const int kq = blockIdx.x & 3;        // split-K quarter
  const int kbase = kq * (NN / 4);
  const int w = t >> 6, L = t & 63, lrow = L & 15, quad = L >> 4;
  const size_t row0 = (size_t)bm * 64;

  auto prefetch = [&](int buf, int k0) {
#pragma unroll
    for (int j = 0; j < 6; ++j) {
      const int g = w * 6 + j;                 // wave-uniform issue id, 0..23
      const int o = g * 1024 + L * 16;         // byte offset in tile image
      const u16* src;
      if (g < 8) {                             // A region (first 8KB, 64 rows)
        const int r = o >> 7, c = (o >> 4) & 7;
        src = Abf + (row0 + r) * NN + (k0 + ((c ^ (r & 7)) << 3));
      } else {                                 // B region (16KB, 128 rows)
        const int o2 = o - 8192;
        const int r = o2 >> 7, c = (o2 >> 4) & 7;
        src = tT + (size_t)r * NN + (k0 + ((c ^ (r & 7)) << 3));
      }
      __builtin_amdgcn_global_load_lds((gvoid*)src,
                                       (lvoid*)&sh[buf][g * 1024], 16, 0, 0);
    }
  };

  f32x4 acc[4][2] = {};
  prefetch(0, kbase);
  __syncthreads();

  for (int it = 0; it < 32; ++it) {
    const int cur = it & 1;
    if (it < 31) prefetch(cur ^ 1, kbase + (it + 1) * 64);
    const unsigned char* Ab = &sh[cur][0];
    const unsigned char* Bb = &sh[cur][8192];
#pragma unroll
    for (int s = 0; s < 2; ++s) {
      const int cx = (((s * 4) | quad) ^ (lrow & 7)) << 4;  // swizzled chunk
      s16x8 fb0 = *(const s16x8*)(Bb + (w * 32 + lrow) * 128 + cx);
      s16x8 fb1 = *(const s16x8*)(Bb + (w * 32 + 16 + lrow) * 128 + cx);
#pragma unroll
      for (int mt = 0; mt < 4; ++mt) {
        s16x8 fa = *(const s16x8*)(Ab + (mt * 16 + lrow) * 128 + cx);
        acc[mt][0] = __builtin_amdgcn_mfma_f32_16x16x32_bf16(fa, fb0, acc[mt][0], 0, 0, 0);
        acc[mt][1] = __builtin_amdgcn_mfma_f32_16x16x32_bf16(fa, fb1, acc[mt][1], 0, 0, 0);
      }
    }
    __syncthreads();
  }

  float* pbase = part + (size_t)kq * NN * DD;
#pragma unroll
  for (int mt = 0; mt < 4; ++mt) {
#pragma unroll
    for (int r = 0; r < 4; ++r) {
      const int i = (int)row0 + mt * 16 + quad * 4 + r;
#pragma unroll
      for (int nt = 0; nt < 2; ++nt) {
        const int n = w * 32 + nt * 16 + lrow;
        pbase[(size_t)i * DD + n] = acc[mt][nt][r];
      }
    }
  }
}

// ---- K4: out[i][n] = dinv[i]*(p0+p1+p2+p3+diag) + bias[n] ----
__global__ __launch_bounds__(256) void k_reduce(const float* __restrict__ part,
                                                const u16* __restrict__ tT,
                                                const float* __restrict__ dinv,
                                                const float* __restrict__ bias,
                                                float* __restrict__ out) {
  const int gid = blockIdx.x * 256 + threadIdx.x;   // 0 .. 262143
  const int i = gid >> 5;
  const int c = gid & 31;                            // n = 4c .. 4c+3
  const size_t idx = (size_t)i * 32 + c;
  const float4 p0 = ((const float4*)part)[idx];
  const float4 p1 = ((const float4*)(part + (size_t)NN * DD))[idx];
  const float4 p2 = ((const float4*)(part + (size_t)2 * NN * DD))[idx];
  const float4 p3 = ((const float4*)(part + (size_t)3 * NN * DD))[idx];
  const float4 bb = ((const float4*)bias)[c];
  const float dv = dinv[i];
  const int n = c * 4;
  float4 o;
  o.x = dv * (((p0.x + p1.x) + (p2.x + p3.x)) + bf2f(tT[(size_t)(n + 0) * NN + i])) + bb.x;
  o.y = dv * (((p0.y + p1.y) + (p2.y + p3.y)) + bf2f(tT[(size_t)(n + 1) * NN + i])) + bb.y;
  o.z = dv * (((p0.z + p1.z) + (p2.z + p3.z)) + bf2f(tT[(size_t)(n + 2) * NN + i])) + bb.z;
  o.w = dv * (((p0.w + p1.w) + (p2.w + p3.w)) + bf2f(tT[(size_t)(n + 3) * NN + i])) + bb.w;
  ((float4*)out)[idx] = o;
}

extern "C" void kernel_launch(void* const* d_in, const int* in_sizes, int n_in,
                              void* d_out, int out_size, void* d_ws, size_t ws_size,
                              hipStream_t stream) {
  const float* X    = (const float*)d_in[0];   // node_features [8192,128]
  const float* A    = (const float*)d_in[1];   // adj_matrix    [8192,8192]
  const float* W    = (const float*)d_in[2];   // weight        [128,128]
  const float* bias = (const float*)d_in[3];   // bias          [128]
  float* out = (float*)d_out;

  float* dinv = (float*)d_ws;                                        // 32 KB
  u16*   tT   = (u16*)((char*)d_ws + 32768);                         // 2 MB
  float* part = (float*)((char*)d_ws + 32768 + 2097152);             // 16 MB
  u16*   Abf  = (u16*)((char*)d_ws + 32768 + 2097152 + 16777216);    // 128 MB

  hipLaunchKernelGGL(k_prep,    dim3(8192), dim3(256), 0, stream, A, dinv, Abf);
  hipLaunchKernelGGL(k_support, dim3(256),  dim3(256), 0, stream, X, W, dinv, tT);
  hipLaunchKernelGGL(k_gemm,    dim3(512),  dim3(256), 0, stream, Abf, tT, part);
  hipLaunchKernelGGL(k_reduce,  dim3(1024), dim3(256), 0, stream, part, tT, dinv, bias, out);
}